// Round 6
// baseline (501.251 us; speedup 1.0000x reference)
//
#include <hip/hip_runtime.h>

// Problem constants (match reference)
#define BATCH   64
#define GH      52
#define GWID    52
#define HW      2704          // GH*GW
#define NA      5
#define NC      80
#define MAXB    30
#define CH_STRIDE HW
#define A_STRIDE  (85*HW)     // 229840 ; note b*B_STRIDE + a*A_STRIDE == ba*A_STRIDE
#define NBA       (BATCH*NA)  // 320

// Workspace layout (ws >= 1 GB):
//   u32 counter        @ 0
//   float partialA[960]@ 1024
//   float partialB[2048]@ 8192
//   u32  desc[..]      @ 16384           (p | ba<<12 | t_cls<<21)
//   float amv[..]      @ 16384 + 4 MB
#define WS_PARTA   1024
#define WS_PARTB   8192
#define WS_DESC    16384
#define WS_AMV     (16384 + (4<<20))

#define GX_DENSE   3          // ceil(676/256); 676 threads of 4 positions cover HW
#define GB_CLASS   2048       // class kernel blocks (x256 thr = 8192 waves)

// ---------------- Kernel A: dense losses + masked-cell compaction ----------------
__global__ __launch_bounds__(256) void yolo_dense(
    const float* __restrict__ net_out,   // (ba, 85, HW)
    const float* __restrict__ targets,   // (ba, 6, HW)
    const float* __restrict__ amask,     // (ba, HW)
    const float* __restrict__ tboxes,    // (B, MAXB, 4)
    const float* __restrict__ anchors,   // (A, 2)
    unsigned*    __restrict__ counter,
    float*       __restrict__ partialA,
    unsigned*    __restrict__ desc,
    float*       __restrict__ amv)
{
    __shared__ float tb[MAXB * 4];
    __shared__ float wred[4];

    const int ba   = blockIdx.y;
    const int b    = ba / NA;
    const int a    = ba - b * NA;
    const int tid  = threadIdx.x;
    const int lane = tid & 63;

    if (tid < MAXB * 4) tb[tid] = tboxes[(size_t)b * (MAXB * 4) + tid];
    __syncthreads();

    const int  p0    = (blockIdx.x * 256 + tid) * 4;
    const bool valid = (p0 < HW);               // 2704 % 4 == 0: thread fully valid or not
    const size_t nb    = (size_t)ba * A_STRIDE + (valid ? p0 : 0);
    const size_t tbase = (size_t)ba * 6 * HW   + (valid ? p0 : 0);

    float zx[4], zy[4], twp[4], thp[4], zc[4];
    float t_x[4], t_y[4], t_w[4], t_h[4], t_c[4], tcl[4], am[4];

    if (valid) {
        float4 v;
        v = *(const float4*)(net_out + nb);                 zx[0]=v.x; zx[1]=v.y; zx[2]=v.z; zx[3]=v.w;
        v = *(const float4*)(net_out + nb + 1*CH_STRIDE);   zy[0]=v.x; zy[1]=v.y; zy[2]=v.z; zy[3]=v.w;
        v = *(const float4*)(net_out + nb + 2*CH_STRIDE);   twp[0]=v.x;twp[1]=v.y;twp[2]=v.z;twp[3]=v.w;
        v = *(const float4*)(net_out + nb + 3*CH_STRIDE);   thp[0]=v.x;thp[1]=v.y;thp[2]=v.z;thp[3]=v.w;
        v = *(const float4*)(net_out + nb + 4*CH_STRIDE);   zc[0]=v.x; zc[1]=v.y; zc[2]=v.z; zc[3]=v.w;
        v = *(const float4*)(targets + tbase);              t_x[0]=v.x;t_x[1]=v.y;t_x[2]=v.z;t_x[3]=v.w;
        v = *(const float4*)(targets + tbase + 1*HW);       t_y[0]=v.x;t_y[1]=v.y;t_y[2]=v.z;t_y[3]=v.w;
        v = *(const float4*)(targets + tbase + 2*HW);       t_w[0]=v.x;t_w[1]=v.y;t_w[2]=v.z;t_w[3]=v.w;
        v = *(const float4*)(targets + tbase + 3*HW);       t_h[0]=v.x;t_h[1]=v.y;t_h[2]=v.z;t_h[3]=v.w;
        v = *(const float4*)(targets + tbase + 4*HW);       t_c[0]=v.x;t_c[1]=v.y;t_c[2]=v.z;t_c[3]=v.w;
        v = *(const float4*)(targets + tbase + 5*HW);       tcl[0]=v.x;tcl[1]=v.y;tcl[2]=v.z;tcl[3]=v.w;
        v = *(const float4*)(amask + (size_t)ba * HW + p0); am[0]=v.x; am[1]=v.y; am[2]=v.z; am[3]=v.w;
    } else {
        #pragma unroll
        for (int j = 0; j < 4; ++j) {
            zx[j]=zy[j]=twp[j]=thp[j]=zc[j]=0.f;
            t_x[j]=t_y[j]=t_w[j]=t_h[j]=t_c[j]=tcl[j]=am[j]=0.f;
        }
    }

    const float aw = anchors[a * 2 + 0];
    const float ah = anchors[a * 2 + 1];

    float sx[4], sy[4], x1[4], y1[4], x2[4], y2[4], a1[4], io[4];
    #pragma unroll
    for (int j = 0; j < 4; ++j) {
        sx[j] = 1.f / (1.f + __builtin_expf(-zx[j]));
        sy[j] = 1.f / (1.f + __builtin_expf(-zy[j]));
        const int p = p0 + j;
        const float px = (sx[j] + (float)(p % GWID)) * (416.f / (float)GWID);
        const float py = (sy[j] + (float)(p / GWID)) * (416.f / (float)GH);
        const float pw = __builtin_expf(twp[j]) * aw;
        const float ph = __builtin_expf(thp[j]) * ah;
        x1[j] = px - pw * 0.5f;
        y1[j] = py - ph * 0.5f;
        x2[j] = x1[j] + pw;
        y2[j] = y1[j] + ph;
        a1[j] = pw * ph;
        io[j] = 0.f;
    }

    #pragma unroll
    for (int k = 0; k < MAXB; ++k) {
        const float bx1 = tb[k * 4 + 0];
        const float by1 = tb[k * 4 + 1];
        const float bx2 = tb[k * 4 + 2];
        const float by2 = tb[k * 4 + 3];
        const float a2  = (bx2 - bx1) * (by2 - by1);
        #pragma unroll
        for (int j = 0; j < 4; ++j) {
            const float wi = fmaxf(fminf(x2[j], bx2) - fmaxf(x1[j], bx1), 0.f);
            const float hi = fmaxf(fminf(y2[j], by2) - fmaxf(y1[j], by1), 0.f);
            const float inter = wi * hi;
            const float iou = inter / (a1[j] + a2 - inter + 1e-5f);
            io[j] = fmaxf(io[j], iou);
        }
    }

    float lsum = 0.f;
    if (valid) {
        #pragma unroll
        for (int j = 0; j < 4; ++j) {
            const float ws = 2.f - t_w[j] * t_h[j] * (1.f / (416.f * 416.f));
            const float dx = sx[j] - t_x[j], dy = sy[j] - t_y[j];
            const float dw = twp[j] - t_w[j], dh = thp[j] - t_h[j];
            const float coords = (dx*dx + dy*dy + dw*dw + dh*dh) * ws * am[j];

            // log(pc) = -log(1+e^-z); log(1-pc) = -log(1+e^z)
            const float log_pc   = -__builtin_logf(1.f + __builtin_expf(-zc[j]));
            const float log_1mpc = -__builtin_logf(1.f + __builtin_expf(zc[j]));
            const float bce = -(t_c[j] * log_pc + (1.f - t_c[j]) * log_1mpc);
            const float pt  = __builtin_expf(-bce);
            const float omp = 1.f - pt;
            const float fl  = omp * omp * bce;

            const float noobj = (io[j] < 0.5f) ? (1.f - am[j]) : 0.f;
            lsum += 5.0f * coords + 5.0f * am[j] * fl + noobj * fl;
        }
    }

    // ---- compaction of masked cells (all lanes participate) ----
    #pragma unroll
    for (int j = 0; j < 4; ++j) {
        const bool m = (am[j] > 0.f);
        const unsigned long long msk = __ballot(m);
        if (msk) {
            unsigned base = 0;
            if (lane == 0) base = atomicAdd(counter, (unsigned)__popcll(msk));
            base = (unsigned)__shfl((int)base, 0, 64);
            if (m) {
                const int rank = __popcll(msk & ((1ull << lane) - 1ull));
                const int p = p0 + j;
                desc[base + rank] = (unsigned)p | ((unsigned)ba << 12)
                                  | ((unsigned)(int)tcl[j] << 21);
                amv[base + rank] = am[j];
            }
        }
    }

    // ---- block reduction ----
    #pragma unroll
    for (int off = 32; off > 0; off >>= 1)
        lsum += __shfl_down(lsum, off, 64);
    const int wid = tid >> 6;
    if (lane == 0) wred[wid] = lsum;
    __syncthreads();
    if (tid == 0)
        partialA[(size_t)blockIdx.y * GX_DENSE + blockIdx.x] =
            wred[0] + wred[1] + wred[2] + wred[3];
}

// ---------------- Kernel B: class loss, one wave per masked cell ----------------
__global__ __launch_bounds__(256) void yolo_class(
    const float*    __restrict__ net_out,
    const unsigned* __restrict__ counter,
    const unsigned* __restrict__ desc,
    const float*    __restrict__ amv,
    float*          __restrict__ partialB)
{
    __shared__ float w4[4];
    const int tid  = threadIdx.x;
    const int lane = tid & 63;
    const int wid  = tid >> 6;
    const int gwave  = blockIdx.x * 4 + wid;
    const int nwaves = gridDim.x * 4;
    const int count  = (int)*counter;

    float acc = 0.f;
    for (int i = gwave; i < count; i += nwaves) {
        const unsigned d   = desc[i];
        const float amv_i  = amv[i];
        const int p    = d & 0xFFF;
        const int bav  = (d >> 12) & 0x1FF;
        const int tcls = (int)(d >> 21);
        const size_t cb = (size_t)bav * A_STRIDE + (size_t)5 * HW + p;

        const float v0 = net_out[cb + (size_t)lane * HW];
        const float v1 = (lane < (NC - 64))
                       ? net_out[cb + (size_t)(64 + lane) * HW]
                       : -1e30f;

        float mx = fmaxf(v0, v1);
        #pragma unroll
        for (int off = 32; off > 0; off >>= 1)
            mx = fmaxf(mx, __shfl_xor(mx, off, 64));

        float e = __builtin_expf(v0 - mx)
                + ((lane < (NC - 64)) ? __builtin_expf(v1 - mx) : 0.f);
        #pragma unroll
        for (int off = 32; off > 0; off >>= 1)
            e += __shfl_xor(e, off, 64);

        const float vt = (tcls < 64) ? __shfl(v0, tcls, 64)
                                     : __shfl(v1, tcls - 64, 64);

        if (lane == 0)
            acc += -(vt - mx - __builtin_logf(e)) * amv_i;   // CLASS_SCALE = 1
    }

    if (lane == 0) w4[wid] = acc;
    __syncthreads();
    if (tid == 0) partialB[blockIdx.x] = w4[0] + w4[1] + w4[2] + w4[3];
}

// ---------------- Kernel C: final reduce ----------------
__global__ __launch_bounds__(256) void yolo_final(
    const float* __restrict__ partialA, int nA,
    const float* __restrict__ partialB, int nB,
    float* __restrict__ out)
{
    __shared__ double sred[4];
    const int tid = threadIdx.x;
    double s = 0.0;
    for (int i = tid; i < nA; i += 256) s += (double)partialA[i];
    for (int i = tid; i < nB; i += 256) s += (double)partialB[i];
    #pragma unroll
    for (int off = 32; off > 0; off >>= 1)
        s += __shfl_down(s, off, 64);
    const int wid  = tid >> 6;
    const int lane = tid & 63;
    if (lane == 0) sred[wid] = s;
    __syncthreads();
    if (tid == 0) {
        const double tot = sred[0] + sred[1] + sred[2] + sred[3];
        out[0] = (float)(tot / (double)BATCH);
    }
}

extern "C" void kernel_launch(void* const* d_in, const int* in_sizes, int n_in,
                              void* d_out, int out_size, void* d_ws, size_t ws_size,
                              hipStream_t stream) {
    const float* net_out = (const float*)d_in[0];
    const float* targets = (const float*)d_in[1];
    const float* amask   = (const float*)d_in[2];
    const float* tboxes  = (const float*)d_in[3];
    const float* anchors = (const float*)d_in[4];

    char* ws = (char*)d_ws;
    unsigned* counter  = (unsigned*)ws;
    float*    partialA = (float*)(ws + WS_PARTA);
    float*    partialB = (float*)(ws + WS_PARTB);
    unsigned* desc     = (unsigned*)(ws + WS_DESC);
    float*    amv      = (float*)(ws + WS_AMV);
    float*    out      = (float*)d_out;

    hipMemsetAsync(counter, 0, 64, stream);

    dim3 gridA(GX_DENSE, NBA);   // (3, 320) = 960 blocks, 4 positions/thread
    yolo_dense<<<gridA, 256, 0, stream>>>(net_out, targets, amask, tboxes, anchors,
                                          counter, partialA, desc, amv);
    yolo_class<<<GB_CLASS, 256, 0, stream>>>(net_out, counter, desc, amv, partialB);
    yolo_final<<<1, 256, 0, stream>>>(partialA, GX_DENSE * NBA, partialB, GB_CLASS, out);
}

// Round 7
// 409.861 us; speedup vs baseline: 1.2230x; 1.2230x over previous
//
#include <hip/hip_runtime.h>

// Problem constants (match reference)
#define BATCH   64
#define GH      52
#define GWID    52
#define HW      2704          // GH*GW
#define NA      5
#define NC      80
#define MAXB    30
#define A_STRIDE  (85*HW)     // ba stride in net_out: b*B_STRIDE + a*A_STRIDE == ba*A_STRIDE
#define NBA       (BATCH*NA)  // 320
#define GX_DENSE  3           // ceil((HW/4)/256) = ceil(676/256)

// Fused kernel: dense losses (float4, 4 positions/thread) + inline
// wave-cooperative class loss on masked cells (~2% density).
// grid (3, 320), block 256.
__global__ __launch_bounds__(256) void yolo_main(
    const float* __restrict__ net_out,   // (ba, 85, HW)
    const float* __restrict__ targets,   // (ba, 6, HW)
    const float* __restrict__ amask,     // (ba, HW)
    const float* __restrict__ tboxes,    // (B, MAXB, 4)
    const float* __restrict__ anchors,   // (A, 2)
    float*       __restrict__ partial)   // (320*3)
{
    __shared__ float tb[MAXB * 4];
    __shared__ float wred[4];

    const int ba   = blockIdx.y;
    const int b    = ba / NA;
    const int a    = ba - b * NA;
    const int tid  = threadIdx.x;
    const int lane = tid & 63;

    if (tid < MAXB * 4) tb[tid] = tboxes[(size_t)b * (MAXB * 4) + tid];
    __syncthreads();

    const int  p0    = (blockIdx.x * 256 + tid) * 4;
    const bool valid = (p0 < HW);               // HW%4==0: thread fully valid or not
    const size_t nb    = (size_t)ba * A_STRIDE + (valid ? p0 : 0);
    const size_t tbase = (size_t)ba * 6 * HW   + (valid ? p0 : 0);

    float zx[4], zy[4], twp[4], thp[4], zc[4];
    float t_x[4], t_y[4], t_w[4], t_h[4], t_c[4], tcl[4], am[4];

    if (valid) {
        float4 v;
        v = *(const float4*)(net_out + nb);            zx[0]=v.x; zx[1]=v.y; zx[2]=v.z; zx[3]=v.w;
        v = *(const float4*)(net_out + nb + 1*HW);     zy[0]=v.x; zy[1]=v.y; zy[2]=v.z; zy[3]=v.w;
        v = *(const float4*)(net_out + nb + 2*HW);     twp[0]=v.x;twp[1]=v.y;twp[2]=v.z;twp[3]=v.w;
        v = *(const float4*)(net_out + nb + 3*HW);     thp[0]=v.x;thp[1]=v.y;thp[2]=v.z;thp[3]=v.w;
        v = *(const float4*)(net_out + nb + 4*HW);     zc[0]=v.x; zc[1]=v.y; zc[2]=v.z; zc[3]=v.w;
        v = *(const float4*)(targets + tbase);         t_x[0]=v.x;t_x[1]=v.y;t_x[2]=v.z;t_x[3]=v.w;
        v = *(const float4*)(targets + tbase + 1*HW);  t_y[0]=v.x;t_y[1]=v.y;t_y[2]=v.z;t_y[3]=v.w;
        v = *(const float4*)(targets + tbase + 2*HW);  t_w[0]=v.x;t_w[1]=v.y;t_w[2]=v.z;t_w[3]=v.w;
        v = *(const float4*)(targets + tbase + 3*HW);  t_h[0]=v.x;t_h[1]=v.y;t_h[2]=v.z;t_h[3]=v.w;
        v = *(const float4*)(targets + tbase + 4*HW);  t_c[0]=v.x;t_c[1]=v.y;t_c[2]=v.z;t_c[3]=v.w;
        v = *(const float4*)(targets + tbase + 5*HW);  tcl[0]=v.x;tcl[1]=v.y;tcl[2]=v.z;tcl[3]=v.w;
        v = *(const float4*)(amask + (size_t)ba * HW + p0); am[0]=v.x; am[1]=v.y; am[2]=v.z; am[3]=v.w;
    } else {
        #pragma unroll
        for (int j = 0; j < 4; ++j) {
            zx[j]=zy[j]=twp[j]=thp[j]=zc[j]=0.f;
            t_x[j]=t_y[j]=t_w[j]=t_h[j]=t_c[j]=tcl[j]=am[j]=0.f;
        }
    }

    const float aw = anchors[a * 2 + 0];
    const float ah = anchors[a * 2 + 1];

    float sx[4], sy[4], x1[4], y1[4], x2[4], y2[4], a1[4], io[4];
    #pragma unroll
    for (int j = 0; j < 4; ++j) {
        sx[j] = 1.f / (1.f + __builtin_expf(-zx[j]));
        sy[j] = 1.f / (1.f + __builtin_expf(-zy[j]));
        const int p = p0 + j;
        const float px = (sx[j] + (float)(p % GWID)) * (416.f / (float)GWID);
        const float py = (sy[j] + (float)(p / GWID)) * (416.f / (float)GH);
        const float pw = __builtin_expf(twp[j]) * aw;
        const float ph = __builtin_expf(thp[j]) * ah;
        x1[j] = px - pw * 0.5f;
        y1[j] = py - ph * 0.5f;
        x2[j] = x1[j] + pw;
        y2[j] = y1[j] + ph;
        a1[j] = pw * ph;
        io[j] = 0.f;
    }

    #pragma unroll
    for (int k = 0; k < MAXB; ++k) {
        const float bx1 = tb[k * 4 + 0];
        const float by1 = tb[k * 4 + 1];
        const float bx2 = tb[k * 4 + 2];
        const float by2 = tb[k * 4 + 3];
        const float a2  = (bx2 - bx1) * (by2 - by1);
        #pragma unroll
        for (int j = 0; j < 4; ++j) {
            const float wi = fmaxf(fminf(x2[j], bx2) - fmaxf(x1[j], bx1), 0.f);
            const float hi = fmaxf(fminf(y2[j], by2) - fmaxf(y1[j], by1), 0.f);
            const float inter = wi * hi;
            const float iou = inter / (a1[j] + a2 - inter + 1e-5f);
            io[j] = fmaxf(io[j], iou);
        }
    }

    float lsum = 0.f;
    #pragma unroll
    for (int j = 0; j < 4; ++j) {
        const float ws = 2.f - t_w[j] * t_h[j] * (1.f / (416.f * 416.f));
        const float dx = sx[j] - t_x[j], dy = sy[j] - t_y[j];
        const float dw = twp[j] - t_w[j], dh = thp[j] - t_h[j];
        const float coords = (dx*dx + dy*dy + dw*dw + dh*dh) * ws * am[j];

        // log(pc) = -log(1+e^-z); log(1-pc) = -log(1+e^z)   (no log1pf on device)
        const float log_pc   = -__builtin_logf(1.f + __builtin_expf(-zc[j]));
        const float log_1mpc = -__builtin_logf(1.f + __builtin_expf(zc[j]));
        const float bce = -(t_c[j] * log_pc + (1.f - t_c[j]) * log_1mpc);
        const float pt  = __builtin_expf(-bce);
        const float omp = 1.f - pt;
        const float fl  = omp * omp * bce;

        const float noobj = (io[j] < 0.5f) ? (1.f - am[j]) : 0.f;
        if (valid)
            lsum += 5.0f * coords + 5.0f * am[j] * fl + noobj * fl;
    }

    // ---- class loss: wave-cooperative over masked cells (~5.3 cells/wave) ----
    const size_t cbase = (size_t)ba * A_STRIDE + (size_t)5 * HW;
    #pragma unroll
    for (int j = 0; j < 4; ++j) {
        unsigned long long mb = __ballot(am[j] > 0.f);
        while (mb) {
            const int src = __ffsll((long long)mb) - 1;
            mb &= mb - 1;
            const int   p_s  = __shfl(p0, src, 64) + j;
            const float am_s = __shfl(am[j], src, 64);
            const int   tc_s = __shfl((int)tcl[j], src, 64);

            const size_t cb = cbase + p_s;
            const float v0 = net_out[cb + (size_t)lane * HW];
            const float v1 = (lane < (NC - 64))
                           ? net_out[cb + (size_t)(64 + lane) * HW]
                           : -1e30f;

            float mx = fmaxf(v0, v1);
            #pragma unroll
            for (int off = 32; off > 0; off >>= 1)
                mx = fmaxf(mx, __shfl_xor(mx, off, 64));

            float e = __builtin_expf(v0 - mx)
                    + ((lane < (NC - 64)) ? __builtin_expf(v1 - mx) : 0.f);
            #pragma unroll
            for (int off = 32; off > 0; off >>= 1)
                e += __shfl_xor(e, off, 64);

            const float vt = (tc_s < 64) ? __shfl(v0, tc_s, 64)
                                         : __shfl(v1, tc_s - 64, 64);

            if (lane == src)
                lsum += -(vt - mx - __builtin_logf(e)) * am_s;  // CLASS_SCALE = 1
        }
    }

    // ---- block reduction ----
    #pragma unroll
    for (int off = 32; off > 0; off >>= 1)
        lsum += __shfl_down(lsum, off, 64);
    const int wid = tid >> 6;
    if (lane == 0) wred[wid] = lsum;
    __syncthreads();
    if (tid == 0)
        partial[(size_t)blockIdx.y * GX_DENSE + blockIdx.x] =
            wred[0] + wred[1] + wred[2] + wred[3];
}

__global__ __launch_bounds__(256) void yolo_final(
    const float* __restrict__ partial, int n, float* __restrict__ out)
{
    __shared__ double sred[4];
    const int tid = threadIdx.x;
    double s = 0.0;
    for (int i = tid; i < n; i += 256) s += (double)partial[i];
    #pragma unroll
    for (int off = 32; off > 0; off >>= 1)
        s += __shfl_down(s, off, 64);
    const int wid  = tid >> 6;
    const int lane = tid & 63;
    if (lane == 0) sred[wid] = s;
    __syncthreads();
    if (tid == 0) {
        const double tot = sred[0] + sred[1] + sred[2] + sred[3];
        out[0] = (float)(tot / (double)BATCH);
    }
}

extern "C" void kernel_launch(void* const* d_in, const int* in_sizes, int n_in,
                              void* d_out, int out_size, void* d_ws, size_t ws_size,
                              hipStream_t stream) {
    const float* net_out = (const float*)d_in[0];
    const float* targets = (const float*)d_in[1];
    const float* amask   = (const float*)d_in[2];
    const float* tboxes  = (const float*)d_in[3];
    const float* anchors = (const float*)d_in[4];
    float* partial = (float*)d_ws;
    float* out = (float*)d_out;

    dim3 grid(GX_DENSE, NBA);   // (3, 320) = 960 blocks, 4 positions/thread
    yolo_main<<<grid, 256, 0, stream>>>(net_out, targets, amask, tboxes, anchors, partial);
    yolo_final<<<1, 256, 0, stream>>>(partial, GX_DENSE * NBA, out);
}